// Round 1
// baseline (144.499 us; speedup 1.0000x reference)
//
#include <hip/hip_runtime.h>

// RNN: h_t = relu(W_ih x_t + b_ih + b_hh + W_hh h_{t-1}); out = fc_w h_T + fc_b
// B=4096, T=512, C=4, H=32, O=3.
// One wave handles 32 batch rows for all 512 steps.
// D[h][b] = W_hh @ H^T via v_mfma_f32_32x32x16_bf16; input projection fused as a
// third MFMA with zero-padded A=W_ih and C preloaded with the bias tile.
// D->next-B fragment conversion is 8x v_cvt_pk_bf16_f32 + 4x v_permlane32_swap_b32.

typedef __attribute__((ext_vector_type(16))) float f32x16;
typedef __attribute__((ext_vector_type(8)))  short short8;

#define DEVI __device__ __forceinline__

constexpr int kB = 4096, kT = 512, kC = 4, kH = 32, kO = 3;

DEVI unsigned cvt_pk_bf16(float lo, float hi) {
    unsigned r;
    asm("v_cvt_pk_bf16_f32 %0, %1, %2" : "=v"(r) : "v"(lo), "v"(hi));
    return r;
}

DEVI short f2bf(float f) {  // RTNE float -> bf16 bits
    union { float f; unsigned u; } x; x.f = f;
    unsigned r = (x.u + 0x7FFFu + ((x.u >> 16) & 1u)) >> 16;
    return (short)(unsigned short)r;
}

union Frag { unsigned u[4]; short8 v; };

__global__ __launch_bounds__(64, 1) void rnn_fused(
    const float* __restrict__ seq,  const float* __restrict__ w_ih,
    const float* __restrict__ w_hh, const float* __restrict__ b_ih,
    const float* __restrict__ b_hh, const float* __restrict__ fc_w,
    const float* __restrict__ fc_b, float* __restrict__ out)
{
    const int lane = threadIdx.x & 63;
    const int c    = lane & 31;   // A-row (hidden out) AND B-col (batch in chunk)
    const int s    = lane >> 5;   // half-wave: selects k-subrange 8s..8s+7
    const int b0   = blockIdx.x * 32;

    // ---- constant A fragments (weights, bf16) ----
    short8 a_ih, a_hh0, a_hh1;
    #pragma unroll
    for (int j = 0; j < 8; ++j) {
        const int k = 8 * s + j;
        a_ih[j]  = (k < kC) ? f2bf(w_ih[c * kC + k]) : (short)0;  // zero-pad K 4->16
        a_hh0[j] = f2bf(w_hh[c * kH + k]);        // K-half 0 (h[0..15])
        a_hh1[j] = f2bf(w_hh[c * kH + 16 + k]);   // K-half 1 (h[16..31])
    }
    // ---- bias tile in D layout: row = (r&3) + 8*(r>>2) + 4*s, col = c ----
    f32x16 bias_tile;
    #pragma unroll
    for (int r = 0; r < 16; ++r) {
        const int row = (r & 3) + 8 * (r >> 2) + 4 * s;
        bias_tile[r] = b_ih[row] + b_hh[row];
    }

    // seq row for batch (b0+c): T contiguous float4 (C=4)
    const float4* sp = reinterpret_cast<const float4*>(seq) + (size_t)(b0 + c) * kT;

    // h as B-fragments (bf16 pairs); h_0 = 0
    unsigned hb[8];
    #pragma unroll
    for (int i = 0; i < 8; ++i) hb[i] = 0u;

    f32x16 acc;  // after each step holds relu'd h (fp32) in D layout

    float4 bufA[4], bufB[4];
    #pragma unroll
    for (int k = 0; k < 4; ++k) bufA[k] = sp[k];

    auto STEP = [&](const float4& sv) {
        // seq -> bf16 packed B fragment (half1 / k>=4 lanes are garbage; A is 0 there)
        const unsigned sq0 = cvt_pk_bf16(sv.x, sv.y);
        const unsigned sq1 = cvt_pk_bf16(sv.z, sv.w);
        Frag bseq; bseq.u[0] = sq0; bseq.u[1] = sq1; bseq.u[2] = sq0; bseq.u[3] = sq1;
        Frag bh0;  bh0.u[0] = hb[0]; bh0.u[1] = hb[1]; bh0.u[2] = hb[2]; bh0.u[3] = hb[3];
        Frag bh1;  bh1.u[0] = hb[4]; bh1.u[1] = hb[5]; bh1.u[2] = hb[6]; bh1.u[3] = hb[7];

        acc = __builtin_amdgcn_mfma_f32_32x32x16_bf16(a_ih,  bseq.v, bias_tile, 0, 0, 0);
        acc = __builtin_amdgcn_mfma_f32_32x32x16_bf16(a_hh0, bh0.v,  acc,       0, 0, 0);
        acc = __builtin_amdgcn_mfma_f32_32x32x16_bf16(a_hh1, bh1.v,  acc,       0, 0, 0);

        #pragma unroll
        for (int r = 0; r < 16; ++r) acc[r] = fmaxf(acc[r], 0.0f);  // relu, in place

        // pack D pairs -> bf16; then permlane32_swap routes D rows into B k-order:
        //   B(kappa) reg m: j0-3 from half0 regs 4(2k+s)..+3, j4-7 from half1 same regs
        unsigned pk[8];
        #pragma unroll
        for (int m = 0; m < 8; ++m) pk[m] = cvt_pk_bf16(acc[2 * m], acc[2 * m + 1]);
        asm("v_permlane32_swap_b32 %0, %1" : "+v"(pk[0]), "+v"(pk[2]));
        asm("v_permlane32_swap_b32 %0, %1" : "+v"(pk[1]), "+v"(pk[3]));
        asm("v_permlane32_swap_b32 %0, %1" : "+v"(pk[4]), "+v"(pk[6]));
        asm("v_permlane32_swap_b32 %0, %1" : "+v"(pk[5]), "+v"(pk[7]));
        #pragma unroll
        for (int i = 0; i < 8; ++i) hb[i] = pk[i];
    };

    for (int t0 = 0; t0 < kT; t0 += 8) {
        #pragma unroll
        for (int k = 0; k < 4; ++k) { int tl = t0 + 4 + k; bufB[k] = sp[tl < kT ? tl : kT - 1]; }
        #pragma unroll
        for (int k = 0; k < 4; ++k) STEP(bufA[k]);
        #pragma unroll
        for (int k = 0; k < 4; ++k) { int tl = t0 + 8 + k; bufA[k] = sp[tl < kT ? tl : kT - 1]; }
        #pragma unroll
        for (int k = 0; k < 4; ++k) STEP(bufB[k]);
    }

    // ---- fc head in fp32 from final acc (= h_last in D layout) ----
    float p0 = 0.f, p1 = 0.f, p2 = 0.f;
    #pragma unroll
    for (int r = 0; r < 16; ++r) {
        const int row = (r & 3) + 8 * (r >> 2) + 4 * s;
        const float h = acc[r];
        p0 += fc_w[0 * kH + row] * h;
        p1 += fc_w[1 * kH + row] * h;
        p2 += fc_w[2 * kH + row] * h;
    }
    p0 += __shfl_xor(p0, 32, 64);
    p1 += __shfl_xor(p1, 32, 64);
    p2 += __shfl_xor(p2, 32, 64);
    if (lane < 32) {
        float* op = out + (size_t)(b0 + c) * kO;
        op[0] = p0 + fc_b[0];
        op[1] = p1 + fc_b[1];
        op[2] = p2 + fc_b[2];
    }
}

extern "C" void kernel_launch(void* const* d_in, const int* in_sizes, int n_in,
                              void* d_out, int out_size, void* d_ws, size_t ws_size,
                              hipStream_t stream) {
    const float* seq  = (const float*)d_in[0];
    const float* w_ih = (const float*)d_in[1];
    const float* w_hh = (const float*)d_in[2];
    const float* b_ih = (const float*)d_in[3];
    const float* b_hh = (const float*)d_in[4];
    const float* fc_w = (const float*)d_in[5];
    const float* fc_b = (const float*)d_in[6];
    float* outp = (float*)d_out;

    rnn_fused<<<dim3(kB / 32), dim3(64), 0, stream>>>(
        seq, w_ih, w_hh, b_ih, b_hh, fc_w, fc_b, outp);
}